// Round 1
// baseline (3790.553 us; speedup 1.0000x reference)
//
#include <hip/hip_runtime.h>
#include <hip/hip_bf16.h>
#include <stdint.h>

// ---------------- problem constants ----------------
constexpr int Hh  = 768;     // hidden
constexpr int Ss  = 256;     // seq len
constexpr int Bb  = 32;      // batch
constexpr int G4  = 4 * Hh;  // 3072 gate cols
constexpr int MR  = Bb * Ss; // 8192 rows of the big GEMMs
constexpr int NWG = 96;      // LSTM workgroups (all co-resident; 96 <= 256 CUs)
constexpr int UPW = Hh / NWG; // hidden units per WG = 8

typedef short bf16x8 __attribute__((ext_vector_type(8)));
typedef float f32x4  __attribute__((ext_vector_type(4)));
typedef float f32x2  __attribute__((ext_vector_type(2)));

__device__ __forceinline__ unsigned short f2bf(float f) {
  union { float f; uint32_t u; } v; v.f = f;
  uint32_t u = v.u;
  return (unsigned short)((u + 0x7FFFu + ((u >> 16) & 1u)) >> 16); // RNE
}
__device__ __forceinline__ float bf2f(unsigned short h) {
  union { uint32_t u; float f; } v; v.u = ((uint32_t)h) << 16; return v.f;
}

// ---------------- embedding gather + bf16 cast ----------------
__global__ __launch_bounds__(256) void k_embed(const int* __restrict__ ids,
                                               const float* __restrict__ table,
                                               unsigned short* __restrict__ x_bf) {
  int row = blockIdx.x;                 // b*S+s
  int id  = ids[row];
  const float* src = table + (size_t)id * Hh;
  unsigned short* dst = x_bf + (size_t)row * Hh;
  for (int j = threadIdx.x; j < Hh; j += 256) dst[j] = f2bf(src[j]);
}

// ---------------- fp32 -> bf16 cast (4 elems/thread) ----------------
__global__ __launch_bounds__(256) void k_cast(const float* __restrict__ src,
                                              unsigned short* __restrict__ dst, int n4) {
  int i = blockIdx.x * 256 + threadIdx.x;
  if (i < n4) {
    float4 v = ((const float4*)src)[i];
    uint2 o;
    o.x = (uint32_t)f2bf(v.x) | ((uint32_t)f2bf(v.y) << 16);
    o.y = (uint32_t)f2bf(v.z) | ((uint32_t)f2bf(v.w) << 16);
    ((uint2*)dst)[i] = o;
  }
}

// ---------------- MFMA bf16 TN GEMM: C[m][n] = sum_k A[m][k]*Bw[n][k] + bias1[n]+bias2[n]
// A (M,K) bf16 row-major, Bw (N,K) bf16 row-major, C (M,N) bf16. M%128==0, N%128==0, K%64==0.
__global__ __launch_bounds__(256) void k_gemm_bt(const unsigned short* __restrict__ A,
                                                 const unsigned short* __restrict__ Bw,
                                                 unsigned short* __restrict__ C,
                                                 const float* __restrict__ bias1,
                                                 const float* __restrict__ bias2,
                                                 int M, int N, int K) {
  constexpr int BM = 128, BN = 128, BK = 64;
  __shared__ unsigned short Asm[BM * BK];  // [row][16B-block swizzled]
  __shared__ unsigned short Bsm[BN * BK];
  const int tid = threadIdx.x, lane = tid & 63, wave = tid >> 6;
  const int m0 = blockIdx.x * BM, n0 = blockIdx.y * BN;
  const int wm = (wave & 1) * 64, wn = (wave >> 1) * 64;

  f32x4 acc[4][4];
  #pragma unroll
  for (int a = 0; a < 4; ++a)
    #pragma unroll
    for (int b = 0; b < 4; ++b) acc[a][b] = (f32x4){0.f, 0.f, 0.f, 0.f};

  const int nk = K / BK;
  bf16x8 ar[4], br[4];
  // prologue loads (it = 0)
  #pragma unroll
  for (int r = 0; r < 4; ++r) {
    int fb = r * 4096 + tid * 16;
    int row = fb >> 7;            // byte row stride = BK*2 = 128
    int kb  = (fb >> 4) & 7;
    ar[r] = *(const bf16x8*)(A  + (size_t)(m0 + row) * K + kb * 8);
    br[r] = *(const bf16x8*)(Bw + (size_t)(n0 + row) * K + kb * 8);
  }
  for (int it = 0; it < nk; ++it) {
    __syncthreads();   // previous compute done -> LDS reusable
    #pragma unroll
    for (int r = 0; r < 4; ++r) {
      int fb = r * 4096 + tid * 16;
      int row = fb >> 7;
      int kb  = (fb >> 4) & 7;
      int sb  = kb ^ (row & 7);   // XOR swizzle (both sides) -> 2-way banks on reads
      *(bf16x8*)((char*)Asm + row * 128 + sb * 16) = ar[r];
      *(bf16x8*)((char*)Bsm + row * 128 + sb * 16) = br[r];
    }
    __syncthreads();
    if (it + 1 < nk) {
      int k0 = (it + 1) * BK;
      #pragma unroll
      for (int r = 0; r < 4; ++r) {
        int fb = r * 4096 + tid * 16;
        int row = fb >> 7;
        int kb  = (fb >> 4) & 7;
        ar[r] = *(const bf16x8*)(A  + (size_t)(m0 + row) * K + k0 + kb * 8);
        br[r] = *(const bf16x8*)(Bw + (size_t)(n0 + row) * K + k0 + kb * 8);
      }
    }
    #pragma unroll
    for (int kk = 0; kk < 2; ++kk) {
      bf16x8 af[4], bfr[4];
      #pragma unroll
      for (int mi = 0; mi < 4; ++mi) {
        int row = wm + mi * 16 + (lane & 15);
        int kb  = kk * 4 + (lane >> 4);
        int sb  = kb ^ (row & 7);
        af[mi] = *(const bf16x8*)((const char*)Asm + row * 128 + sb * 16);
      }
      #pragma unroll
      for (int ni = 0; ni < 4; ++ni) {
        int row = wn + ni * 16 + (lane & 15);
        int kb  = kk * 4 + (lane >> 4);
        int sb  = kb ^ (row & 7);
        bfr[ni] = *(const bf16x8*)((const char*)Bsm + row * 128 + sb * 16);
      }
      #pragma unroll
      for (int mi = 0; mi < 4; ++mi)
        #pragma unroll
        for (int ni = 0; ni < 4; ++ni)
          acc[mi][ni] = __builtin_amdgcn_mfma_f32_16x16x32_bf16(af[mi], bfr[ni], acc[mi][ni], 0, 0, 0);
    }
  }
  // epilogue: D layout col=lane&15, row=(lane>>4)*4+reg  [verified layout]
  #pragma unroll
  for (int mi = 0; mi < 4; ++mi)
    #pragma unroll
    for (int ni = 0; ni < 4; ++ni)
      #pragma unroll
      for (int r = 0; r < 4; ++r) {
        int row = wm + mi * 16 + (lane >> 4) * 4 + r;
        int col = wn + ni * 16 + (lane & 15);
        float v = acc[mi][ni][r] + bias1[n0 + col] + bias2[n0 + col];
        C[(size_t)(m0 + row) * N + n0 + col] = f2bf(v);
      }
}

// ---------------- LSTM recurrence (one layer), flag-synced persistent WGs --------
// g_bf: (B,S,4H) precomputed x@W_ih^T + biases (bf16). w_bf: (4H,H) bf16.
// out_bf: (B,S,H) bf16 = the h sequence (also next-step A operand).
// done[t]: #WGs that completed step t (zeroed before launch).
__global__ __launch_bounds__(256) void k_lstm(const unsigned short* __restrict__ g_bf,
                                              const unsigned short* __restrict__ w_bf,
                                              unsigned short* __restrict__ out_bf,
                                              int* __restrict__ done) {
  __shared__ unsigned short Bsm[32][Hh + 8];   // [gate col][k], padded to kill bank conflicts
  __shared__ float gsm[Bb][32];
  __shared__ float csm[Bb * UPW];
  __shared__ unsigned short hsm[Bb * UPW];

  const int tid = threadIdx.x, lane = tid & 63, wave = tid >> 6;
  const int u0 = blockIdx.x * UPW;

  // persistent weight slice: gate cols {gi*H + u0+u : gi in 0..3, u in 0..7}
  for (int lc = 0; lc < 32; ++lc) {
    int gi = lc >> 3, u = lc & 7;
    const unsigned short* src = w_bf + (size_t)(gi * Hh + u0 + u) * Hh;
    for (int k = tid; k < Hh; k += 256) Bsm[lc][k] = src[k];
  }
  if (tid < Bb * UPW) csm[tid] = 0.f;
  __syncthreads();

  const int mtile = wave & 1, ntile = wave >> 1;
  const int col   = ntile * 16 + (lane & 15);   // local gate col 0..31
  const int gi    = col >> 3, uu = col & 7;
  const int gcol  = gi * Hh + u0 + uu;          // global gate col
  const int brow  = mtile * 16 + (lane & 15);   // batch row for A operand
  const int kq    = lane >> 4;                  // 0..3

  for (int t = 0; t < Ss; ++t) {
    if (t > 0) {
      if (tid == 0) {
        while (__hip_atomic_load(done + (t - 1), __ATOMIC_RELAXED, __HIP_MEMORY_SCOPE_AGENT) < NWG)
          __builtin_amdgcn_s_sleep(2);
      }
      __syncthreads();
      asm volatile("" ::: "memory");
    }
    // precomputed input-gate values, 4 per lane (D-layout rows)
    float gin[4];
    #pragma unroll
    for (int r = 0; r < 4; ++r) {
      int b = mtile * 16 + kq * 4 + r;
      gin[r] = bf2f(g_bf[((size_t)b * Ss + t) * G4 + gcol]);
    }
    f32x4 acc = {0.f, 0.f, 0.f, 0.f};
    if (t > 0) {
      // h_{t-1} @ W_hh^T : A = out_bf[:, t-1, :]  (fresh lines every t -> no stale caches)
      bf16x8 areg[24];
      const unsigned short* ap = out_bf + ((size_t)brow * Ss + (t - 1)) * Hh + kq * 8;
      #pragma unroll
      for (int kk = 0; kk < 24; ++kk) areg[kk] = *(const bf16x8*)(ap + kk * 32);
      #pragma unroll
      for (int kk = 0; kk < 24; ++kk) {
        bf16x8 bfr = *(const bf16x8*)(&Bsm[col][kk * 32 + kq * 8]);
        acc = __builtin_amdgcn_mfma_f32_16x16x32_bf16(areg[kk], bfr, acc, 0, 0, 0);
      }
    }
    // activations: gi==2 -> tanh, else sigmoid
    #pragma unroll
    for (int r = 0; r < 4; ++r) {
      float v = acc[r] + gin[r];
      float a;
      if (gi == 2) { float e = __expf(-2.f * v); a = (1.f - e) / (1.f + e); }
      else         { a = 1.f / (1.f + __expf(-v)); }
      int b = mtile * 16 + kq * 4 + r;
      gsm[b][col] = a;
    }
    __syncthreads();
    // pointwise c/h update: 256 threads = 32 batches x 8 units
    {
      const int b = tid >> 3, u = tid & 7;
      float iv = gsm[b][u], fv = gsm[b][8 + u], gv = gsm[b][16 + u], ov = gsm[b][24 + u];
      float c = fv * csm[tid] + iv * gv;
      csm[tid] = c;
      float e = __expf(-2.f * c);
      hsm[tid] = f2bf(ov * (1.f - e) / (1.f + e));
    }
    __syncthreads();
    // publish h through the coherent point (device-scope stores bypass local L2)
    if (tid < 128) {
      int b = tid >> 2, j = tid & 3;
      uint32_t v = ((const uint32_t*)hsm)[tid];
      __hip_atomic_store((uint32_t*)(out_bf + ((size_t)b * Ss + t) * Hh + u0 + j * 2),
                         v, __ATOMIC_RELAXED, __HIP_MEMORY_SCOPE_AGENT);
    }
    asm volatile("s_waitcnt vmcnt(0)" ::: "memory");  // all h stores acked at coherent point
    __syncthreads();
    if (tid == 0) atomicAdd(done + t, 1);             // device-scope release of step t
  }
}

// ---------------- pool partial: partial[s][b][n] = sum_h out2[b,s,h]*pool_w[s*H+h][n]
__global__ __launch_bounds__(256) void k_pool_partial(const unsigned short* __restrict__ out2,
                                                      const float* __restrict__ pw,
                                                      float* __restrict__ partial) {
  __shared__ unsigned short osm[Hh * Bb];  // [k][b] bf16
  const int tid = threadIdx.x;
  const int s = blockIdx.x;
  for (int b = 0; b < Bb; ++b) {
    const unsigned short* src = out2 + ((size_t)b * Ss + s) * Hh;
    for (int k = tid; k < Hh; k += 256) osm[k * Bb + b] = src[k];
  }
  __syncthreads();
  f32x2 acc[16][3];
  #pragma unroll
  for (int bp = 0; bp < 16; ++bp)
    #pragma unroll
    for (int j = 0; j < 3; ++j) acc[bp][j] = (f32x2){0.f, 0.f};
  const float* pbase = pw + (size_t)s * Hh * Hh;
  #pragma unroll 2
  for (int k = 0; k < Hh; ++k) {
    float w0 = pbase[(size_t)k * Hh + tid];
    float w1 = pbase[(size_t)k * Hh + 256 + tid];
    float w2 = pbase[(size_t)k * Hh + 512 + tid];
    const uint32_t* orow = (const uint32_t*)&osm[k * Bb];
    #pragma unroll
    for (int bp = 0; bp < 16; ++bp) {
      uint32_t pv = orow[bp];
      f32x2 ov;
      ov.x = __uint_as_float(pv << 16);
      ov.y = __uint_as_float(pv & 0xffff0000u);
      acc[bp][0] += ov * w0;
      acc[bp][1] += ov * w1;
      acc[bp][2] += ov * w2;
    }
  }
  float* pout = partial + (size_t)s * (Bb * Hh);
  #pragma unroll
  for (int bp = 0; bp < 16; ++bp)
    #pragma unroll
    for (int j = 0; j < 3; ++j) {
      pout[(size_t)(bp * 2 + 0) * Hh + j * 256 + tid] = acc[bp][j].x;
      pout[(size_t)(bp * 2 + 1) * Hh + j * 256 + tid] = acc[bp][j].y;
    }
}

__global__ __launch_bounds__(256) void k_pool_reduce(const float* __restrict__ partial,
                                                     const float* __restrict__ pool_b,
                                                     float* __restrict__ seq_out) {
  int i = blockIdx.x * 256 + threadIdx.x;  // b*H+n
  float acc = pool_b[i % Hh];
  #pragma unroll 8
  for (int t = 0; t < Ss; ++t) acc += partial[(size_t)t * (Bb * Hh) + i];
  seq_out[i] = acc;
}

// ---------------- entity masked max + logits ----------------
__global__ __launch_bounds__(256) void k_entity_logits(const unsigned short* __restrict__ out2,
                                                       const float* __restrict__ seq_out,
                                                       const int* __restrict__ entity_ids,
                                                       const float* __restrict__ lin_w,
                                                       const float* __restrict__ lin_b,
                                                       float* __restrict__ logits_ws,
                                                       float* __restrict__ dlogits) {
  const int b = blockIdx.x, tid = threadIdx.x;
  float m0 = -1e30f, m1 = -1e30f, m2 = -1e30f;
  for (int s = 0; s < Ss; ++s) {
    bool e = entity_ids[b * Ss + s] == 1;
    const unsigned short* row = out2 + ((size_t)b * Ss + s) * Hh;
    float v0 = bf2f(row[tid]);
    float v1 = bf2f(row[256 + tid]);
    float v2 = bf2f(row[512 + tid]);
    v0 = e ? v0 : 0.f; v1 = e ? v1 : 0.f; v2 = e ? v2 : 0.f;
    m0 = fmaxf(m0, v0); m1 = fmaxf(m1, v1); m2 = fmaxf(m2, v2);
  }
  __shared__ float red[512];
  float p0 = 0.f, p1 = 0.f;
  float mm[3] = {m0, m1, m2};
  #pragma unroll
  for (int j = 0; j < 3; ++j) {
    int n = j * 256 + tid;
    float bo = fmaxf(mm[j], seq_out[b * Hh + n]);
    p0 += bo * lin_w[n * 2 + 0];
    p1 += bo * lin_w[n * 2 + 1];
  }
  red[tid] = p0; red[256 + tid] = p1;
  __syncthreads();
  for (int off = 128; off > 0; off >>= 1) {
    if (tid < off) { red[tid] += red[tid + off]; red[256 + tid] += red[256 + tid + off]; }
    __syncthreads();
  }
  if (tid == 0) {
    float l0 = red[0] + lin_b[0], l1 = red[256] + lin_b[1];
    logits_ws[b * 2] = l0; logits_ws[b * 2 + 1] = l1;
    dlogits[b * 2] = l0;  dlogits[b * 2 + 1] = l1;
  }
}

// ---------------- BCEWithLogits mean loss ----------------
__global__ void k_loss(const float* __restrict__ logits, const int* __restrict__ lab,
                       float* __restrict__ dout) {
  __shared__ float red[64];
  int i = threadIdx.x;
  float l = logits[i];
  float y = (float)lab[i];
  red[i] = fmaxf(l, 0.f) - l * y + log1pf(__expf(-fabsf(l)));
  __syncthreads();
  for (int off = 32; off > 0; off >>= 1) {
    if (i < off) red[i] += red[i + off];
    __syncthreads();
  }
  if (i == 0) dout[0] = red[0] * (1.f / 64.f);
}

// ---------------- launcher ----------------
extern "C" void kernel_launch(void* const* d_in, const int* in_sizes, int n_in,
                              void* d_out, int out_size, void* d_ws, size_t ws_size,
                              hipStream_t stream) {
  const int*   input_ids  = (const int*)d_in[0];
  const int*   seq_label  = (const int*)d_in[3];
  const int*   entity_ids = (const int*)d_in[4];
  const float* embed      = (const float*)d_in[5];
  const float* w_ih0      = (const float*)d_in[6];
  const float* w_hh0      = (const float*)d_in[7];
  const float* b_ih0      = (const float*)d_in[8];
  const float* b_hh0      = (const float*)d_in[9];
  const float* w_ih1      = (const float*)d_in[10];
  const float* w_hh1      = (const float*)d_in[11];
  const float* b_ih1      = (const float*)d_in[12];
  const float* b_hh1      = (const float*)d_in[13];
  const float* pool_w     = (const float*)d_in[14];
  const float* pool_b     = (const float*)d_in[15];
  const float* lin_w      = (const float*)d_in[16];
  const float* lin_b      = (const float*)d_in[17];
  float* out = (float*)d_out;

  const size_t SZ_XO = (size_t)Bb * Ss * Hh * 2;   // 12,582,912 (x_bf, later out2)
  const size_t SZ_W  = (size_t)G4 * Hh * 2;        //  4,718,592 per weight matrix
  const size_t SZ_G  = (size_t)Bb * Ss * G4 * 2;   // 50,331,648 (g1/g2, later partial)
  char* ws = (char*)d_ws;
  size_t off = 0;
  unsigned short* x_bf   = (unsigned short*)(ws + off); off += SZ_XO;   // also out2
  unsigned short* wb_ih0 = (unsigned short*)(ws + off); off += SZ_W;
  unsigned short* wb_hh0 = (unsigned short*)(ws + off); off += SZ_W;
  unsigned short* wb_ih1 = (unsigned short*)(ws + off); off += SZ_W;
  unsigned short* wb_hh1 = (unsigned short*)(ws + off); off += SZ_W;
  unsigned short* g_bf   = (unsigned short*)(ws + off);                 // also partial
  float*          partial= (float*)(ws + off);          off += SZ_G;
  unsigned short* out1_bf= (unsigned short*)(ws + off); off += SZ_XO;
  float*          seq_out= (float*)(ws + off);          off += (size_t)Bb * Hh * 4;
  float*          logits = (float*)(ws + off);          off += 1024;
  int*            done   = (int*)(ws + off);            off += 2 * Ss * sizeof(int);
  unsigned short* out2_bf = x_bf;  // x consumed by GEMM1 before LSTM2 writes out2

  hipMemsetAsync(done, 0, 2 * Ss * sizeof(int), stream);

  k_embed<<<Bb * Ss, 256, 0, stream>>>(input_ids, embed, x_bf);
  int n4 = (G4 * Hh) / 4;
  int cgrid = (n4 + 255) / 256;
  k_cast<<<cgrid, 256, 0, stream>>>(w_ih0, wb_ih0, n4);
  k_cast<<<cgrid, 256, 0, stream>>>(w_hh0, wb_hh0, n4);
  k_cast<<<cgrid, 256, 0, stream>>>(w_ih1, wb_ih1, n4);
  k_cast<<<cgrid, 256, 0, stream>>>(w_hh1, wb_hh1, n4);

  dim3 ggrid(MR / 128, G4 / 128);
  k_gemm_bt<<<ggrid, 256, 0, stream>>>(x_bf, wb_ih0, g_bf, b_ih0, b_hh0, MR, G4, Hh);
  k_lstm<<<NWG, 256, 0, stream>>>(g_bf, wb_hh0, out1_bf, done);
  k_gemm_bt<<<ggrid, 256, 0, stream>>>(out1_bf, wb_ih1, g_bf, b_ih1, b_hh1, MR, G4, Hh);
  k_lstm<<<NWG, 256, 0, stream>>>(g_bf, wb_hh1, out2_bf, done + Ss);

  k_pool_partial<<<Ss, 256, 0, stream>>>(out2_bf, pool_w, partial);
  k_pool_reduce<<<(Bb * Hh) / 256, 256, 0, stream>>>(partial, pool_b, seq_out);
  k_entity_logits<<<Bb, 256, 0, stream>>>(out2_bf, seq_out, entity_ids, lin_w, lin_b,
                                          logits, out + 1);
  k_loss<<<1, 64, 0, stream>>>(logits, seq_label, out);
}